// Round 4
// baseline (2973.958 us; speedup 1.0000x reference)
//
#include <hip/hip_runtime.h>
#include <math.h>

#define N_TOK 131072
#define VOCAB 50257
#define DIM   512
#define K_CON 512
#define NPARTS 12565   // ceil(VOCAB/4)

// d_out layout (float32 elements)
#define OFF_ENC  ((size_t)0)
#define OFF_QW   ((size_t)67108864)
#define OFF_DOCU ((size_t)134217728)
#define OFF_OUT  ((size_t)134218240)
#define OFF_VQ   ((size_t)134268497)
#define OFF_LTS  ((size_t)134268498)

// ws layout (bytes)
#define WS_COUNTS 0        // 512 * u32
#define WS_VQ     2048     // double
#define WS_LTS    2056     // double
#define WS_SUMV   2072     // double
#define WS_NFLAG  2080     // u32
#define WS_NARR   4096     // 512 f32
#define WS_SARR   6144     // 512 f32
#define WS_BINC   8192     // VOCAB u32
#define WS_LOGITS 209920   // VOCAB f32 (holds exp(logit))
#define WS_FLAGS  411648   // FLAG_CAP u32
#define WS_PART   444416   // NPARTS double
#define FLAG_CAP  8192

typedef __attribute__((ext_vector_type(4)))  float f32x4;
typedef __attribute__((ext_vector_type(8)))  short s16x8;
typedef __attribute__((ext_vector_type(16))) float f32x16;

// Codebook in bf16 hi/lo, MFMA fragment layout:
// tile per step s (16 fp32 dims): [g 0..3][concept 0..511] x s16x8
//   g = hv for hi, 2+hv for lo ; hv selects dims s*16+hv*8..+7
__device__ short g_B2[32 * 4 * 512 * 8];   // 1 MB, L2-resident

__device__ inline unsigned short f2bf(float f) {
    unsigned u = __float_as_uint(f);
    unsigned r = (u + 0x7fffu + ((u >> 16) & 1u)) >> 16;
    return (unsigned short)r;
}
__device__ inline float bf2f(unsigned short h) {
    return __uint_as_float(((unsigned)h) << 16);
}

__device__ __forceinline__ void load_b(int s, int hv, int cbase, s16x8* b) {
    const s16x8* bt = (const s16x8*)g_B2 + (size_t)s * 2048;
    #pragma unroll
    for (int n = 0; n < 4; ++n) {
        b[2*n]   = bt[hv * 512 + cbase + n * 32];
        b[2*n+1] = bt[(2 + hv) * 512 + cbase + n * 32];
    }
}
__device__ __forceinline__ void load_a(const float* xr0, const float* xr1,
                                       int s, int hv, float4* a) {
    const float* p0 = xr0 + s * 16 + hv * 8;
    const float* p1 = xr1 + s * 16 + hv * 8;
    a[0] = *(const float4*)p0; a[1] = *(const float4*)(p0 + 4);
    a[2] = *(const float4*)p1; a[3] = *(const float4*)(p1 + 4);
}
__device__ __forceinline__ void conv4(const float4* a, s16x8* f) {
    float x0[8] = {a[0].x,a[0].y,a[0].z,a[0].w,a[1].x,a[1].y,a[1].z,a[1].w};
    float x1[8] = {a[2].x,a[2].y,a[2].z,a[2].w,a[3].x,a[3].y,a[3].z,a[3].w};
    s16x8 h0, l0, h1, l1;
    #pragma unroll
    for (int e = 0; e < 8; ++e) {
        unsigned short b0 = f2bf(x0[e]);
        h0[e] = (short)b0; l0[e] = (short)f2bf(x0[e] - bf2f(b0));
        unsigned short b1 = f2bf(x1[e]);
        h1[e] = (short)b1; l1[e] = (short)f2bf(x1[e] - bf2f(b1));
    }
    f[0] = h0; f[1] = l0; f[2] = h1; f[3] = l1;
}
__device__ __forceinline__ void do_mfma(f32x16* a0, f32x16* a1,
                                        const s16x8* f, const s16x8* b) {
    #pragma unroll
    for (int n = 0; n < 4; ++n) {
        s16x8 bh = b[2*n], bl = b[2*n+1];
        a0[n] = __builtin_amdgcn_mfma_f32_32x32x16_bf16(f[0], bh, a0[n], 0, 0, 0);
        a0[n] = __builtin_amdgcn_mfma_f32_32x32x16_bf16(f[0], bl, a0[n], 0, 0, 0);
        a0[n] = __builtin_amdgcn_mfma_f32_32x32x16_bf16(f[1], bh, a0[n], 0, 0, 0);
        a1[n] = __builtin_amdgcn_mfma_f32_32x32x16_bf16(f[2], bh, a1[n], 0, 0, 0);
        a1[n] = __builtin_amdgcn_mfma_f32_32x32x16_bf16(f[2], bl, a1[n], 0, 0, 0);
        a1[n] = __builtin_amdgcn_mfma_f32_32x32x16_bf16(f[3], bh, a1[n], 0, 0, 0);
    }
}

// ---------------------------------------------------------------------------
// merged: n/s arrays + codebook bf16 hi/lo prep
__global__ void k_nsprep(const float* __restrict__ cw, float* __restrict__ n_arr,
                         float* __restrict__ s_arr, short* __restrict__ b2) {
    int w = threadIdx.x >> 6, lane = threadIdx.x & 63;
    int r = blockIdx.x * 4 + w;
    const float* row = cw + (size_t)r * DIM;
    {
        float4 a = *(const float4*)(row + lane * 8);
        float4 b = *(const float4*)(row + lane * 8 + 4);
        float v[8] = {a.x,a.y,a.z,a.w,b.x,b.y,b.z,b.w};
        double na = 0.0, sa = 0.0;
        #pragma unroll
        for (int e = 0; e < 8; ++e) { na += (double)v[e]*v[e]; sa += (double)v[e]; }
        for (int off = 32; off; off >>= 1) {
            na += __shfl_down(na, off);
            sa += __shfl_down(sa, off);
        }
        if (lane == 0) { n_arr[r] = (float)na; s_arr[r] = (float)sa; }
    }
    {
        int s = lane >> 1, hf = lane & 1;
        const float* p = row + s * 16 + hf * 8;
        float4 xa = *(const float4*)p;
        float4 xb = *(const float4*)(p + 4);
        float xf[8] = {xa.x,xa.y,xa.z,xa.w,xb.x,xb.y,xb.z,xb.w};
        s16x8 h8, l8;
        #pragma unroll
        for (int e = 0; e < 8; ++e) {
            unsigned short hb = f2bf(xf[e]);
            h8[e] = (short)hb;
            l8[e] = (short)f2bf(xf[e] - bf2f(hb));
        }
        size_t tb = (size_t)s * 16384;
        *(s16x8*)&b2[tb + ((size_t)(hf * 512 + r)) * 8]       = h8;
        *(s16x8*)&b2[tb + ((size_t)((2 + hf) * 512 + r)) * 8] = l8;
    }
}

// ---------------------------------------------------------------------------
// Main: bf16-split MFMA distance GEMM, all-register pipeline, no K-loop
// barriers. Wave wv owns concepts wv*128..+127, all 64 tokens.
__global__ __launch_bounds__(256, 2)
void k_main(const int* __restrict__ doc, const float* __restrict__ emb,
            const float* __restrict__ cw, const float* __restrict__ n_arr,
            float* __restrict__ out, unsigned* __restrict__ counts,
            unsigned* __restrict__ binc,
            double* __restrict__ vq_acc, unsigned* __restrict__ nflag,
            unsigned* __restrict__ flag_list) {
    __shared__ float nsl[512];
    __shared__ float nxs[64];
    __shared__ uint4 redv[4][64];
    __shared__ int docs[64];
    __shared__ int idxs[64];
    __shared__ double dred[256];

    const int tid   = threadIdx.x;
    const int n0    = blockIdx.x * 64;
    const int lane  = tid & 63;
    const int wv    = tid >> 6;
    const int hv    = lane >> 5;
    const int ln31  = lane & 31;
    const int cbase = wv * 128 + ln31;

    if (tid < 64) docs[tid] = doc[n0 + tid];
    nsl[tid]       = n_arr[tid];
    nsl[tid + 256] = n_arr[tid + 256];
    __syncthreads();

    // nx pre-pass: 4 threads per token (also warms L2 with the x rows)
    {
        int t = tid >> 2, q = tid & 3;
        const float* xr = emb + (size_t)docs[t] * DIM + q * 128;
        double px = 0.0;
        for (int f = 0; f < 32; ++f) {
            float4 v = *(const float4*)(xr + f * 4);
            px += (double)v.x*v.x + (double)v.y*v.y + (double)v.z*v.z + (double)v.w*v.w;
        }
        dred[tid] = px;
    }
    __syncthreads();
    if (tid < 64)
        nxs[tid] = (float)(dred[tid*4] + dred[tid*4+1] + dred[tid*4+2] + dred[tid*4+3]);

    const float* xr0 = emb + (size_t)docs[ln31] * DIM;
    const float* xr1 = emb + (size_t)docs[ln31 + 32] * DIM;

    f32x16 acc0[4], acc1[4];
    #pragma unroll
    for (int n = 0; n < 4; ++n) { acc0[n] = (f32x16)(0.0f); acc1[n] = (f32x16)(0.0f); }

    s16x8 bA[8], bB[8], fA[4], fB[4];
    float4 aA[4], aB[4];

    load_b(0, hv, cbase, bA); load_a(xr0, xr1, 0, hv, aA);
    load_b(1, hv, cbase, bB); load_a(xr0, xr1, 1, hv, aB);
    conv4(aA, fA);

    for (int s = 0; s < 30; s += 2) {
        do_mfma(acc0, acc1, fA, bA);
        conv4(aB, fB);
        load_b(s + 2, hv, cbase, bA); load_a(xr0, xr1, s + 2, hv, aA);
        do_mfma(acc0, acc1, fB, bB);
        conv4(aA, fA);
        load_b(s + 3, hv, cbase, bB); load_a(xr0, xr1, s + 3, hv, aB);
    }
    do_mfma(acc0, acc1, fA, bA);
    conv4(aB, fB);
    do_mfma(acc0, acc1, fB, bB);

    __syncthreads();   // nxs visible to all; K-loop had no barriers

    float nsv[4];
    #pragma unroll
    for (int n = 0; n < 4; ++n) nsv[n] = nsl[cbase + n * 32];

    // per-row argmin + second best; C/D: col=lane&31, row=(r&3)+8*(r>>2)+4*hv
    #pragma unroll
    for (int m = 0; m < 2; ++m) {
        const f32x16* am = m ? acc1 : acc0;
        #pragma unroll
        for (int r = 0; r < 16; ++r) {
            int tt = (r & 3) + ((r >> 2) << 3) + (hv << 2);   // 0..31
            float nxr = nxs[m * 32 + tt];
            float v1 = INFINITY, v2 = INFINITY; int j1 = 0x7fffffff;
            #pragma unroll
            for (int n = 0; n < 4; ++n) {
                float d = fmaf(-2.f, am[n][r], nxr + nsv[n]);
                int jj = cbase + n * 32;
                if (d < v1) { v2 = v1; v1 = d; j1 = jj; }
                else if (d < v2) { v2 = d; }
            }
            #pragma unroll
            for (int off = 1; off < 32; off <<= 1) {
                float ov1 = __shfl_xor(v1, off);
                int   oj1 = __shfl_xor(j1, off);
                float ov2 = __shfl_xor(v2, off);
                v2 = fminf(fminf(v2, ov2), fmaxf(v1, ov1));
                bool take = (ov1 < v1) || (ov1 == v1 && oj1 < j1);
                if (take) { v1 = ov1; j1 = oj1; }
            }
            if (ln31 == 0)
                redv[wv][m * 32 + tt] = make_uint4(__float_as_uint(v1), (unsigned)j1,
                                                   __float_as_uint(v2), 0u);
        }
    }
    __syncthreads();
    double myv1 = 0.0;
    if (tid < 64) {
        uint4 a = redv[0][tid];
        float v1 = __uint_as_float(a.x), v2 = __uint_as_float(a.z);
        int j1 = (int)a.y;
        #pragma unroll
        for (int w = 1; w < 4; ++w) {
            uint4 b = redv[w][tid];
            float wv1 = __uint_as_float(b.x), wv2 = __uint_as_float(b.z);
            v2 = fminf(fminf(v2, wv2), fmaxf(v1, wv1));
            bool take = (wv1 < v1) || (wv1 == v1 && (int)b.y < j1);
            if (take) { v1 = wv1; j1 = (int)b.y; }
        }
        idxs[tid] = j1;
        atomicAdd(&counts[j1], 1u);
        atomicAdd(&binc[docs[tid]], 1u);
        myv1 = (double)v1;
        if (v2 - v1 <= 2e-7f) {
            unsigned p = atomicAdd(nflag, 1u);
            if (p < FLAG_CAP) flag_list[p] = (unsigned)(n0 + tid);
        }
    }
    dred[tid] = myv1;
    __syncthreads();

    // encodings: one-hot rows (nontemporal streaming output)
    for (int lin = tid; lin < 8192; lin += 256) {
        int t = lin >> 7, f4 = lin & 127;
        int idx = idxs[t];
        int b4 = f4 << 2;
        f32x4 v;
        v.x = (idx == b4)     ? 1.f : 0.f;
        v.y = (idx == b4 + 1) ? 1.f : 0.f;
        v.z = (idx == b4 + 2) ? 1.f : 0.f;
        v.w = (idx == b4 + 3) ? 1.f : 0.f;
        __builtin_nontemporal_store(v,
            (f32x4*)(out + OFF_ENC + ((size_t)(n0 + t) << 9) + (size_t)b4));
    }
    // quantized_words = codebook rows
    for (int lin = tid; lin < 8192; lin += 256) {
        int t = lin >> 7, f4 = lin & 127;
        f32x4 c4 = *(const f32x4*)(cw + (size_t)idxs[t] * DIM + (f4 << 2));
        __builtin_nontemporal_store(c4,
            (f32x4*)(out + OFF_QW + ((size_t)(n0 + t) << 9) + (size_t)(f4 << 2)));
    }
    // vq partial reduce
    for (int st = 128; st; st >>= 1) {
        if (tid < st) dred[tid] += dred[tid + st];
        __syncthreads();
    }
    if (tid == 0) atomicAdd(vq_acc, dred[0]);
}

// ---------------------------------------------------------------------------
// Exact fp32 recompute for flagged near-tie tokens; patches outputs in place.
__global__ __launch_bounds__(512)
void k_fixup(const int* __restrict__ doc, const float* __restrict__ emb,
             const float* __restrict__ cw, const float* __restrict__ n_arr,
             const unsigned* __restrict__ nflag, const unsigned* __restrict__ flag_list,
             float* __restrict__ out, unsigned* __restrict__ counts,
             double* __restrict__ vq_acc) {
    __shared__ float xs[512];
    __shared__ float nxsh;
    __shared__ int oldj_sh;
    __shared__ float vsh[512];
    __shared__ unsigned long long keys[512];

    const int tid = threadIdx.x;
    unsigned nf = *nflag;
    if (nf > FLAG_CAP) nf = FLAG_CAP;

    for (unsigned f = blockIdx.x; f < nf; f += gridDim.x) {
        int t = (int)flag_list[f];
        int dc = doc[t];
        if (tid < 128)
            *(float4*)&xs[tid * 4] = *(const float4*)(emb + (size_t)dc * DIM + tid * 4);
        if (tid == 0) oldj_sh = -1;
        __syncthreads();
        if (tid == 0) {
            double p[4];
            for (int q = 0; q < 4; ++q) {
                double px = 0.0;
                for (int fq = 0; fq < 32; ++fq) {
                    float4 v = *(const float4*)&xs[q * 128 + fq * 4];
                    px += (double)v.x*v.x + (double)v.y*v.y + (double)v.z*v.z + (double)v.w*v.w;
                }
                p[q] = px;
            }
            nxsh = (float)(((p[0] + p[1]) + p[2]) + p[3]);
        }
        {
            float e = out[OFF_ENC + (size_t)t * 512 + tid];
            if (e == 1.0f) oldj_sh = tid;
        }
        __syncthreads();
        {
            const float* cr = cw + (size_t)tid * DIM;
            float dot = 0.f;
            for (int d = 0; d < 512; ++d) dot = fmaf(xs[d], cr[d], dot);
            float v = fmaf(-2.f, dot, nxsh + n_arr[tid]);
            vsh[tid] = v;
            keys[tid] = (((unsigned long long)__float_as_uint(v)) << 32) | (unsigned)tid;
        }
        __syncthreads();
        for (int st = 256; st; st >>= 1) {
            if (tid < st) {
                unsigned long long o = keys[tid + st];
                if (o < keys[tid]) keys[tid] = o;
            }
            __syncthreads();
        }
        int newj = (int)(keys[0] & 0xffffffffu);
        int oldj = oldj_sh;
        if (newj != oldj) {
            if (tid == 0) {
                out[OFF_ENC + (size_t)t * 512 + oldj] = 0.0f;
                out[OFF_ENC + (size_t)t * 512 + newj] = 1.0f;
                atomicSub(&counts[oldj], 1u);
                atomicAdd(&counts[newj], 1u);
                atomicAdd(vq_acc, (double)vsh[newj] - (double)vsh[oldj]);
            }
            if (tid < 128) {
                float4 cn = *(const float4*)(cw + (size_t)newj * DIM + tid * 4);
                *(float4*)&out[OFF_QW + (size_t)t * 512 + tid * 4] = cn;
            }
        }
        __syncthreads();
    }
}

// ---------------------------------------------------------------------------
__global__ void k_docu(const unsigned* __restrict__ counts,
                       const float* __restrict__ cw, float* __restrict__ out_docu) {
    __shared__ float cnt[512];
    int tid = threadIdx.x;
    cnt[tid] = (float)counts[tid];
    __syncthreads();
    double a = 0.0;
    for (int j = 0; j < K_CON; ++j)
        a += (double)cnt[j] * (double)cw[(size_t)j * DIM + tid];
    out_docu[tid] = (float)(a * (1.0 / (double)N_TOK));
}

__global__ __launch_bounds__(256)
void k_lts(const float* __restrict__ cw, const float* __restrict__ n_arr,
           const float* __restrict__ s_arr, double* __restrict__ lts_acc) {
    __shared__ float ci[4 * 512];
    __shared__ float cjs[64 * 68];
    __shared__ double dred[256];
    const int tid = threadIdx.x;
    const int i0 = blockIdx.x * 4;
    #pragma unroll
    for (int rep = 0; rep < 2; ++rep) {
        int lin = rep * 256 + tid;
        int r = lin >> 7, fq = lin & 127;
        *(float4*)&ci[r*512 + fq*4] = *(const float4*)(cw + (size_t)(i0+r)*DIM + fq*4);
    }
    const int jj = tid & 63, ih = tid >> 6;
    const int ig = i0 + ih;
    const float ni = n_arr[ig], si = s_arr[ig];
    const float EPS = 1e-6f;
    double lsum = 0.0;
    for (int jc = 0; jc < 8; ++jc) {
        float accv = 0.f;
        for (int dc = 0; dc < 8; ++dc) {
            __syncthreads();
            #pragma unroll
            for (int rep = 0; rep < 4; ++rep) {
                int lin = rep * 256 + tid;
                int j = lin >> 4, fq = lin & 15;
                float4 v = *(const float4*)(cw + (size_t)(jc*64 + j)*DIM + dc*64 + fq*4);
                cjs[(fq*4+0)*68 + j] = v.x; cjs[(fq*4+1)*68 + j] = v.y;
                cjs[(fq*4+2)*68 + j] = v.z; cjs[(fq*4+3)*68 + j] = v.w;
            }
            __syncthreads();
            #pragma unroll 4
            for (int d = 0; d < 64; ++d)
                accv = fmaf(ci[ih*512 + dc*64 + d], cjs[d*68 + jj], accv);
        }
        int jg = jc*64 + jj;
        float ddv = ni + n_arr[jg] - 2.f*accv + 2.f*EPS*(si - s_arr[jg]) + 512.f*EPS*EPS;
        float dist = sqrtf(fmaxf(ddv, 0.f));
        lsum += (double)((ig == jg) ? dist : fmaxf(0.f, 1.f - dist));
    }
    dred[tid] = lsum;
    __syncthreads();
    for (int s = 128; s; s >>= 1) {
        if (tid < s) dred[tid] += dred[tid + s];
        __syncthreads();
    }
    if (tid == 0) atomicAdd(lts_acc, dred[0]);
}

// logits -> e = exp(logit + bias), per-block partial sums (no max: |logit| tiny)
__global__ void k_logexp(const float* __restrict__ docu, const float* __restrict__ q2w,
                         const float* __restrict__ q2b, float* __restrict__ evals,
                         double* __restrict__ parts) {
    __shared__ double esh[4];
    int wvi = threadIdx.x >> 6, lane = threadIdx.x & 63;
    int v = blockIdx.x * 4 + wvi;
    if (lane == 0) esh[wvi] = 0.0;
    float e = 0.f;
    if (v < VOCAB) {
        const float* wr = q2w + (size_t)v * DIM;
        float4 a = *(const float4*)(wr + lane*8);
        float4 b = *(const float4*)(wr + lane*8 + 4);
        float4 da = *(const float4*)(docu + lane*8);
        float4 db = *(const float4*)(docu + lane*8 + 4);
        float p = a.x*da.x + a.y*da.y + a.z*da.z + a.w*da.w
                + b.x*db.x + b.y*db.y + b.z*db.z + b.w*db.w;
        for (int off = 32; off; off >>= 1) p += __shfl_down(p, off);
        if (lane == 0) {
            e = expf(p + q2b[v]);
            evals[v] = e;
            esh[wvi] = (double)e;
        }
    }
    __syncthreads();
    if (threadIdx.x == 0)
        parts[blockIdx.x] = esh[0] + esh[1] + esh[2] + esh[3];
}

__global__ void k_sumred(const double* __restrict__ parts, double* __restrict__ sumv) {
    __shared__ double red[256];
    int tid = threadIdx.x;
    double s = 0.0;
    for (int i = tid; i < NPARTS; i += 256) s += parts[i];
    red[tid] = s; __syncthreads();
    for (int st = 128; st; st >>= 1) {
        if (tid < st) red[tid] += red[tid + st];
        __syncthreads();
    }
    if (tid == 0) *sumv = red[0];
}

__global__ void k_final(const float* __restrict__ evals,
                        const double* __restrict__ sumv, const unsigned* __restrict__ binc,
                        const double* __restrict__ vq_acc, const double* __restrict__ lts_acc,
                        float* __restrict__ out) {
    int v = blockIdx.x * 256 + threadIdx.x;
    if (v < VOCAB) {
        float s = (float)(*sumv);
        float p = evals[v] / s;
        out[OFF_OUT + v] = logf(p + 1e-6f) * (float)binc[v];
    }
    if (v == 0) {
        out[OFF_VQ]  = (float)(1.25 * (*vq_acc) * (1.0 / 67108864.0));
        out[OFF_LTS] = (float)((*lts_acc) * (1.0 / 262144.0));
    }
}

// ---------------------------------------------------------------------------
extern "C" void kernel_launch(void* const* d_in, const int* in_sizes, int n_in,
                              void* d_out, int out_size, void* d_ws, size_t ws_size,
                              hipStream_t stream) {
    const int*   doc = (const int*)d_in[0];
    const float* emb = (const float*)d_in[1];
    const float* cw  = (const float*)d_in[2];
    const float* q2w = (const float*)d_in[3];
    const float* q2b = (const float*)d_in[4];
    float* out = (float*)d_out;
    char* ws = (char*)d_ws;

    unsigned* counts = (unsigned*)(ws + WS_COUNTS);
    double*   vq_acc = (double*)(ws + WS_VQ);
    double*   lts_acc= (double*)(ws + WS_LTS);
    double*   sumv   = (double*)(ws + WS_SUMV);
    unsigned* nflag  = (unsigned*)(ws + WS_NFLAG);
    float*    n_arr  = (float*)(ws + WS_NARR);
    float*    s_arr  = (float*)(ws + WS_SARR);
    unsigned* binc   = (unsigned*)(ws + WS_BINC);
    float*    evals  = (float*)(ws + WS_LOGITS);
    unsigned* flags  = (unsigned*)(ws + WS_FLAGS);
    double*   parts  = (double*)(ws + WS_PART);

    short* b2;
    hipGetSymbolAddress((void**)&b2, HIP_SYMBOL(g_B2));

    hipMemsetAsync(ws, 0, 4096, stream);
    hipMemsetAsync(binc, 0, VOCAB * sizeof(unsigned), stream);

    hipLaunchKernelGGL(k_nsprep, dim3(128),  dim3(256), 0, stream, cw, n_arr, s_arr, b2);
    hipLaunchKernelGGL(k_main,   dim3(2048), dim3(256), 0, stream, doc, emb, cw, n_arr,
                       out, counts, binc, vq_acc, nflag, flags);
    hipLaunchKernelGGL(k_fixup,  dim3(256),  dim3(512), 0, stream, doc, emb, cw, n_arr,
                       nflag, flags, out, counts, vq_acc);
    hipLaunchKernelGGL(k_docu,   dim3(1),    dim3(512), 0, stream, counts, cw, out + OFF_DOCU);
    hipLaunchKernelGGL(k_lts,    dim3(128),  dim3(256), 0, stream, cw, n_arr, s_arr, lts_acc);
    hipLaunchKernelGGL(k_logexp, dim3(NPARTS), dim3(256), 0, stream,
                       out + OFF_DOCU, q2w, q2b, evals, parts);
    hipLaunchKernelGGL(k_sumred, dim3(1), dim3(256), 0, stream, parts, sumv);
    hipLaunchKernelGGL(k_final,  dim3((VOCAB + 255) / 256), dim3(256), 0, stream,
                       evals, sumv, binc, vq_acc, lts_acc, out);
}

// Round 5
// 659.744 us; speedup vs baseline: 4.5077x; 4.5077x over previous
//
#include <hip/hip_runtime.h>
#include <math.h>

#define N_TOK 131072
#define VOCAB 50257
#define DIM   512
#define K_CON 512
#define NPARTS 12565   // ceil(VOCAB/4)

// d_out layout (float32 elements)
#define OFF_ENC  ((size_t)0)
#define OFF_QW   ((size_t)67108864)
#define OFF_DOCU ((size_t)134217728)
#define OFF_OUT  ((size_t)134218240)
#define OFF_VQ   ((size_t)134268497)
#define OFF_LTS  ((size_t)134268498)

// ws layout (bytes)
#define WS_COUNTS 0        // 512 * u32
#define WS_VQ     2048     // double
#define WS_LTS    2056     // double
#define WS_SUMV   2072     // double
#define WS_NFLAG  2080     // u32
#define WS_NARR   4096     // 512 f32
#define WS_SARR   6144     // 512 f32
#define WS_BINC   8192     // VOCAB u32
#define WS_LOGITS 209920   // VOCAB f32 (holds exp(logit))
#define WS_FLAGS  411648   // FLAG_CAP u32
#define WS_PART   444416   // NPARTS double
#define FLAG_CAP  8192

typedef __attribute__((ext_vector_type(4)))  float f32x4;
typedef __attribute__((ext_vector_type(8)))  short s16x8;
typedef __attribute__((ext_vector_type(16))) float f32x16;

// Codebook in bf16 hi/lo, MFMA fragment layout:
// tile per step s (16 fp32 dims): [g 0..3][concept 0..511] x s16x8
//   g = hv for hi, 2+hv for lo ; hv selects dims s*16+hv*8..+7
__device__ short g_B2[32 * 4 * 512 * 8];   // 1 MB, L2-resident

__device__ inline unsigned short f2bf(float f) {
    unsigned u = __float_as_uint(f);
    unsigned r = (u + 0x7fffu + ((u >> 16) & 1u)) >> 16;
    return (unsigned short)r;
}
__device__ inline float bf2f(unsigned short h) {
    return __uint_as_float(((unsigned)h) << 16);
}

__device__ inline void gload16(const void* g, void* l) {
    __builtin_amdgcn_global_load_lds(
        (const __attribute__((address_space(1))) unsigned int*)g,
        (__attribute__((address_space(3))) unsigned int*)l, 16, 0, 0);
}

__device__ __forceinline__ void load_a(const float* xr0, const float* xr1,
                                       int s, int hv, float4* a) {
    const float* p0 = xr0 + s * 16 + hv * 8;
    const float* p1 = xr1 + s * 16 + hv * 8;
    a[0] = *(const float4*)p0; a[1] = *(const float4*)(p0 + 4);
    a[2] = *(const float4*)p1; a[3] = *(const float4*)(p1 + 4);
}
__device__ __forceinline__ void conv4(const float4* a, s16x8* f) {
    float x0[8] = {a[0].x,a[0].y,a[0].z,a[0].w,a[1].x,a[1].y,a[1].z,a[1].w};
    float x1[8] = {a[2].x,a[2].y,a[2].z,a[2].w,a[3].x,a[3].y,a[3].z,a[3].w};
    s16x8 h0, l0, h1, l1;
    #pragma unroll
    for (int e = 0; e < 8; ++e) {
        unsigned short b0 = f2bf(x0[e]);
        h0[e] = (short)b0; l0[e] = (short)f2bf(x0[e] - bf2f(b0));
        unsigned short b1 = f2bf(x1[e]);
        h1[e] = (short)b1; l1[e] = (short)f2bf(x1[e] - bf2f(b1));
    }
    f[0] = h0; f[1] = l0; f[2] = h1; f[3] = l1;
}
__device__ __forceinline__ void do_mfma(f32x16* a0, f32x16* a1,
                                        const s16x8* f, const s16x8* b) {
    #pragma unroll
    for (int n = 0; n < 4; ++n) {
        s16x8 bh = b[2*n], bl = b[2*n+1];
        a0[n] = __builtin_amdgcn_mfma_f32_32x32x16_bf16(f[0], bh, a0[n], 0, 0, 0);
        a0[n] = __builtin_amdgcn_mfma_f32_32x32x16_bf16(f[0], bl, a0[n], 0, 0, 0);
        a0[n] = __builtin_amdgcn_mfma_f32_32x32x16_bf16(f[1], bh, a0[n], 0, 0, 0);
        a1[n] = __builtin_amdgcn_mfma_f32_32x32x16_bf16(f[2], bh, a1[n], 0, 0, 0);
        a1[n] = __builtin_amdgcn_mfma_f32_32x32x16_bf16(f[2], bl, a1[n], 0, 0, 0);
        a1[n] = __builtin_amdgcn_mfma_f32_32x32x16_bf16(f[3], bh, a1[n], 0, 0, 0);
    }
}

// ---------------------------------------------------------------------------
// merged: n/s arrays + codebook bf16 hi/lo prep
__global__ void k_nsprep(const float* __restrict__ cw, float* __restrict__ n_arr,
                         float* __restrict__ s_arr, short* __restrict__ b2) {
    int w = threadIdx.x >> 6, lane = threadIdx.x & 63;
    int r = blockIdx.x * 4 + w;
    const float* row = cw + (size_t)r * DIM;
    {
        float4 a = *(const float4*)(row + lane * 8);
        float4 b = *(const float4*)(row + lane * 8 + 4);
        float v[8] = {a.x,a.y,a.z,a.w,b.x,b.y,b.z,b.w};
        double na = 0.0, sa = 0.0;
        #pragma unroll
        for (int e = 0; e < 8; ++e) { na += (double)v[e]*v[e]; sa += (double)v[e]; }
        for (int off = 32; off; off >>= 1) {
            na += __shfl_down(na, off);
            sa += __shfl_down(sa, off);
        }
        if (lane == 0) { n_arr[r] = (float)na; s_arr[r] = (float)sa; }
    }
    {
        int s = lane >> 1, hf = lane & 1;
        const float* p = row + s * 16 + hf * 8;
        float4 xa = *(const float4*)p;
        float4 xb = *(const float4*)(p + 4);
        float xf[8] = {xa.x,xa.y,xa.z,xa.w,xb.x,xb.y,xb.z,xb.w};
        s16x8 h8, l8;
        #pragma unroll
        for (int e = 0; e < 8; ++e) {
            unsigned short hb = f2bf(xf[e]);
            h8[e] = (short)hb;
            l8[e] = (short)f2bf(xf[e] - bf2f(hb));
        }
        size_t tb = (size_t)s * 16384;
        *(s16x8*)&b2[tb + ((size_t)(hf * 512 + r)) * 8]       = h8;
        *(s16x8*)&b2[tb + ((size_t)((2 + hf) * 512 + r)) * 8] = l8;
    }
}

// ---------------------------------------------------------------------------
// Main: bf16-split MFMA distance GEMM. Wave wv owns concepts wv*128..+127,
// all 64 tokens. B in LDS double-buffer, counted-vmcnt pipeline (no drains):
//   step s: vmcnt(12) ; bar ; ds_read 8 frags + conv A(s) ; lgkmcnt(0) ;
//           bar ; issue A(s+2) + staging(s+2)->same buf ; 24 MFMA.
__global__ __launch_bounds__(256, 2)
void k_main(const int* __restrict__ doc, const float* __restrict__ emb,
            const float* __restrict__ cw, const float* __restrict__ n_arr,
            float* __restrict__ out, unsigned* __restrict__ counts,
            unsigned* __restrict__ binc,
            double* __restrict__ vq_acc, unsigned* __restrict__ nflag,
            unsigned* __restrict__ flag_list) {
    __shared__ s16x8 bsh0[4 * 512];   // 32 KB buffer A (even steps)
    __shared__ s16x8 bsh1[4 * 512];   // 32 KB buffer B (odd steps)
    __shared__ float nsl[512];
    __shared__ float nxs[64];
    __shared__ uint4 redv[4][64];
    __shared__ int docs[64];
    __shared__ int idxs[64];
    __shared__ double dred[256];

    const int tid   = threadIdx.x;
    const int n0    = blockIdx.x * 64;
    const int lane  = tid & 63;
    const int wv    = tid >> 6;
    const int hv    = lane >> 5;
    const int ln31  = lane & 31;
    const int cbase = wv * 128 + ln31;

    if (tid < 64) docs[tid] = doc[n0 + tid];
    nsl[tid]       = n_arr[tid];
    nsl[tid + 256] = n_arr[tid + 256];
    __syncthreads();

    const float* xr0 = emb + (size_t)docs[ln31] * DIM;
    const float* xr1 = emb + (size_t)docs[ln31 + 32] * DIM;

    float4 aA[4], aB[4];

#define STAGE_STEP(S, DST)                                                    \
    {                                                                         \
        const char* b2t = (const char*)g_B2 + (size_t)(S) * 16384;            \
        char* dstb = (char*)(DST);                                            \
        _Pragma("unroll")                                                     \
        for (int i = 0; i < 8; ++i)                                           \
            gload16(b2t + ((i * 4 + wv) << 10) + (lane << 4),                 \
                    dstb + ((i * 4 + wv) << 10));                             \
    }

    // prologue: stage steps 0,1 + A(0),A(1); all drained by pre-pass barrier
    STAGE_STEP(0, bsh0);
    STAGE_STEP(1, bsh1);
    load_a(xr0, xr1, 0, hv, aA);
    load_a(xr0, xr1, 1, hv, aB);

    // nx pre-pass: 4 threads per token, double partials
    {
        int t = tid >> 2, q = tid & 3;
        const float* xr = emb + (size_t)docs[t] * DIM + q * 128;
        double px = 0.0;
        for (int f = 0; f < 32; ++f) {
            float4 v = *(const float4*)(xr + f * 4);
            px += (double)v.x*v.x + (double)v.y*v.y + (double)v.z*v.z + (double)v.w*v.w;
        }
        dred[tid] = px;
    }
    __syncthreads();   // full drain (one-time): staging 0/1 + A + nx loads
    if (tid < 64)
        nxs[tid] = (float)(dred[tid*4] + dred[tid*4+1] + dred[tid*4+2] + dred[tid*4+3]);
    __syncthreads();   // nxs visible; vmem queue empty here

    f32x16 acc0[4], acc1[4];
    #pragma unroll
    for (int n = 0; n < 4; ++n) { acc0[n] = (f32x16)(0.0f); acc1[n] = (f32x16)(0.0f); }

    s16x8 bfr[8], frg[4];

#define K_READ(BUF)                                                           \
    _Pragma("unroll")                                                         \
    for (int n = 0; n < 4; ++n) {                                             \
        bfr[2*n]   = (BUF)[hv * 512 + cbase + n * 32];                        \
        bfr[2*n+1] = (BUF)[(2 + hv) * 512 + cbase + n * 32];                  \
    }

#define K_STEP(S, BUF, AREG, WAITSTR, ISSUE)                                  \
    asm volatile(WAITSTR ::: "memory");                                       \
    __builtin_amdgcn_sched_barrier(0);                                        \
    __builtin_amdgcn_s_barrier();                                             \
    __builtin_amdgcn_sched_barrier(0);                                        \
    K_READ(BUF);                                                              \
    conv4(AREG, frg);                                                         \
    asm volatile("s_waitcnt lgkmcnt(0)" ::: "memory");                        \
    __builtin_amdgcn_sched_barrier(0);                                        \
    __builtin_amdgcn_s_barrier();                                             \
    __builtin_amdgcn_sched_barrier(0);                                        \
    if (ISSUE) {                                                              \
        load_a(xr0, xr1, (S) + 2, hv, AREG);                                  \
        STAGE_STEP((S) + 2, BUF);                                             \
    }                                                                         \
    do_mfma(acc0, acc1, frg, bfr);

    #pragma unroll 1
    for (int s2 = 0; s2 < 15; ++s2) {
        int s = s2 * 2;
        K_STEP(s,     bsh0, aA, "s_waitcnt vmcnt(12)", true);
        K_STEP(s + 1, bsh1, aB, "s_waitcnt vmcnt(12)", true);
    }
    K_STEP(30, bsh0, aA, "s_waitcnt vmcnt(12)", false);
    K_STEP(31, bsh1, aB, "s_waitcnt vmcnt(0)",  false);

#undef K_STEP
#undef K_READ
#undef STAGE_STEP

    float nsv[4];
    #pragma unroll
    for (int n = 0; n < 4; ++n) nsv[n] = nsl[cbase + n * 32];

    // per-row argmin + second best; C/D: col=lane&31, row=(r&3)+8*(r>>2)+4*hv
    #pragma unroll
    for (int m = 0; m < 2; ++m) {
        const f32x16* am = m ? acc1 : acc0;
        #pragma unroll
        for (int r = 0; r < 16; ++r) {
            int tt = (r & 3) + ((r >> 2) << 3) + (hv << 2);   // 0..31
            float nxr = nxs[m * 32 + tt];
            float v1 = INFINITY, v2 = INFINITY; int j1 = 0x7fffffff;
            #pragma unroll
            for (int n = 0; n < 4; ++n) {
                float d = fmaf(-2.f, am[n][r], nxr + nsv[n]);
                int jj = cbase + n * 32;
                if (d < v1) { v2 = v1; v1 = d; j1 = jj; }
                else if (d < v2) { v2 = d; }
            }
            #pragma unroll
            for (int off = 1; off < 32; off <<= 1) {
                float ov1 = __shfl_xor(v1, off);
                int   oj1 = __shfl_xor(j1, off);
                float ov2 = __shfl_xor(v2, off);
                v2 = fminf(fminf(v2, ov2), fmaxf(v1, ov1));
                bool take = (ov1 < v1) || (ov1 == v1 && oj1 < j1);
                if (take) { v1 = ov1; j1 = oj1; }
            }
            if (ln31 == 0)
                redv[wv][m * 32 + tt] = make_uint4(__float_as_uint(v1), (unsigned)j1,
                                                   __float_as_uint(v2), 0u);
        }
    }
    __syncthreads();
    double myv1 = 0.0;
    if (tid < 64) {
        uint4 a = redv[0][tid];
        float v1 = __uint_as_float(a.x), v2 = __uint_as_float(a.z);
        int j1 = (int)a.y;
        #pragma unroll
        for (int w = 1; w < 4; ++w) {
            uint4 b = redv[w][tid];
            float wv1 = __uint_as_float(b.x), wv2 = __uint_as_float(b.z);
            v2 = fminf(fminf(v2, wv2), fmaxf(v1, wv1));
            bool take = (wv1 < v1) || (wv1 == v1 && (int)b.y < j1);
            if (take) { v1 = wv1; j1 = (int)b.y; }
        }
        idxs[tid] = j1;
        atomicAdd(&counts[j1], 1u);
        atomicAdd(&binc[docs[tid]], 1u);
        myv1 = (double)v1;
        if (v2 - v1 <= 2e-7f) {
            unsigned p = atomicAdd(nflag, 1u);
            if (p < FLAG_CAP) flag_list[p] = (unsigned)(n0 + tid);
        }
    }
    dred[tid] = myv1;
    __syncthreads();

    // encodings: one-hot rows (nontemporal streaming output)
    for (int lin = tid; lin < 8192; lin += 256) {
        int t = lin >> 7, f4 = lin & 127;
        int idx = idxs[t];
        int b4 = f4 << 2;
        f32x4 v;
        v.x = (idx == b4)     ? 1.f : 0.f;
        v.y = (idx == b4 + 1) ? 1.f : 0.f;
        v.z = (idx == b4 + 2) ? 1.f : 0.f;
        v.w = (idx == b4 + 3) ? 1.f : 0.f;
        __builtin_nontemporal_store(v,
            (f32x4*)(out + OFF_ENC + ((size_t)(n0 + t) << 9) + (size_t)b4));
    }
    // quantized_words = codebook rows
    for (int lin = tid; lin < 8192; lin += 256) {
        int t = lin >> 7, f4 = lin & 127;
        f32x4 c4 = *(const f32x4*)(cw + (size_t)idxs[t] * DIM + (f4 << 2));
        __builtin_nontemporal_store(c4,
            (f32x4*)(out + OFF_QW + ((size_t)(n0 + t) << 9) + (size_t)(f4 << 2)));
    }
    // vq partial reduce
    for (int st = 128; st; st >>= 1) {
        if (tid < st) dred[tid] += dred[tid + st];
        __syncthreads();
    }
    if (tid == 0) atomicAdd(vq_acc, dred[0]);
}

// ---------------------------------------------------------------------------
// Exact fp32 recompute for flagged near-tie tokens; patches outputs in place.
__global__ __launch_bounds__(512)
void k_fixup(const int* __restrict__ doc, const float* __restrict__ emb,
             const float* __restrict__ cw, const float* __restrict__ n_arr,
             const unsigned* __restrict__ nflag, const unsigned* __restrict__ flag_list,
             float* __restrict__ out, unsigned* __restrict__ counts,
             double* __restrict__ vq_acc) {
    __shared__ float xs[512];
    __shared__ float nxsh;
    __shared__ int oldj_sh;
    __shared__ float vsh[512];
    __shared__ unsigned long long keys[512];

    const int tid = threadIdx.x;
    unsigned nf = *nflag;
    if (nf > FLAG_CAP) nf = FLAG_CAP;

    for (unsigned f = blockIdx.x; f < nf; f += gridDim.x) {
        int t = (int)flag_list[f];
        int dc = doc[t];
        if (tid < 128)
            *(float4*)&xs[tid * 4] = *(const float4*)(emb + (size_t)dc * DIM + tid * 4);
        if (tid == 0) oldj_sh = -1;
        __syncthreads();
        if (tid == 0) {
            double p[4];
            for (int q = 0; q < 4; ++q) {
                double px = 0.0;
                for (int fq = 0; fq < 32; ++fq) {
                    float4 v = *(const float4*)&xs[q * 128 + fq * 4];
                    px += (double)v.x*v.x + (double)v.y*v.y + (double)v.z*v.z + (double)v.w*v.w;
                }
                p[q] = px;
            }
            nxsh = (float)(((p[0] + p[1]) + p[2]) + p[3]);
        }
        {
            float e = out[OFF_ENC + (size_t)t * 512 + tid];
            if (e == 1.0f) oldj_sh = tid;
        }
        __syncthreads();
        {
            const float* cr = cw + (size_t)tid * DIM;
            float dot = 0.f;
            for (int d = 0; d < 512; ++d) dot = fmaf(xs[d], cr[d], dot);
            float v = fmaf(-2.f, dot, nxsh + n_arr[tid]);
            vsh[tid] = v;
            keys[tid] = (((unsigned long long)__float_as_uint(v)) << 32) | (unsigned)tid;
        }
        __syncthreads();
        for (int st = 256; st; st >>= 1) {
            if (tid < st) {
                unsigned long long o = keys[tid + st];
                if (o < keys[tid]) keys[tid] = o;
            }
            __syncthreads();
        }
        int newj = (int)(keys[0] & 0xffffffffu);
        int oldj = oldj_sh;
        if (newj != oldj) {
            if (tid == 0) {
                out[OFF_ENC + (size_t)t * 512 + oldj] = 0.0f;
                out[OFF_ENC + (size_t)t * 512 + newj] = 1.0f;
                atomicSub(&counts[oldj], 1u);
                atomicAdd(&counts[newj], 1u);
                atomicAdd(vq_acc, (double)vsh[newj] - (double)vsh[oldj]);
            }
            if (tid < 128) {
                float4 cn = *(const float4*)(cw + (size_t)newj * DIM + tid * 4);
                *(float4*)&out[OFF_QW + (size_t)t * 512 + tid * 4] = cn;
            }
        }
        __syncthreads();
    }
}

// ---------------------------------------------------------------------------
__global__ void k_docu(const unsigned* __restrict__ counts,
                       const float* __restrict__ cw, float* __restrict__ out_docu) {
    __shared__ float cnt[512];
    int tid = threadIdx.x;
    cnt[tid] = (float)counts[tid];
    __syncthreads();
    double a = 0.0;
    for (int j = 0; j < K_CON; ++j)
        a += (double)cnt[j] * (double)cw[(size_t)j * DIM + tid];
    out_docu[tid] = (float)(a * (1.0 / (double)N_TOK));
}

__global__ __launch_bounds__(256)
void k_lts(const float* __restrict__ cw, const float* __restrict__ n_arr,
           const float* __restrict__ s_arr, double* __restrict__ lts_acc) {
    __shared__ float ci[4 * 512];
    __shared__ float cjs[64 * 68];
    __shared__ double dred[256];
    const int tid = threadIdx.x;
    const int i0 = blockIdx.x * 4;
    #pragma unroll
    for (int rep = 0; rep < 2; ++rep) {
        int lin = rep * 256 + tid;
        int r = lin >> 7, fq = lin & 127;
        *(float4*)&ci[r*512 + fq*4] = *(const float4*)(cw + (size_t)(i0+r)*DIM + fq*4);
    }
    const int jj = tid & 63, ih = tid >> 6;
    const int ig = i0 + ih;
    const float ni = n_arr[ig], si = s_arr[ig];
    const float EPS = 1e-6f;
    double lsum = 0.0;
    for (int jc = 0; jc < 8; ++jc) {
        float accv = 0.f;
        for (int dc = 0; dc < 8; ++dc) {
            __syncthreads();
            #pragma unroll
            for (int rep = 0; rep < 4; ++rep) {
                int lin = rep * 256 + tid;
                int j = lin >> 4, fq = lin & 15;
                float4 v = *(const float4*)(cw + (size_t)(jc*64 + j)*DIM + dc*64 + fq*4);
                cjs[(fq*4+0)*68 + j] = v.x; cjs[(fq*4+1)*68 + j] = v.y;
                cjs[(fq*4+2)*68 + j] = v.z; cjs[(fq*4+3)*68 + j] = v.w;
            }
            __syncthreads();
            #pragma unroll 4
            for (int d = 0; d < 64; ++d)
                accv = fmaf(ci[ih*512 + dc*64 + d], cjs[d*68 + jj], accv);
        }
        int jg = jc*64 + jj;
        float ddv = ni + n_arr[jg] - 2.f*accv + 2.f*EPS*(si - s_arr[jg]) + 512.f*EPS*EPS;
        float dist = sqrtf(fmaxf(ddv, 0.f));
        lsum += (double)((ig == jg) ? dist : fmaxf(0.f, 1.f - dist));
    }
    dred[tid] = lsum;
    __syncthreads();
    for (int s = 128; s; s >>= 1) {
        if (tid < s) dred[tid] += dred[tid + s];
        __syncthreads();
    }
    if (tid == 0) atomicAdd(lts_acc, dred[0]);
}

// logits -> e = exp(logit + bias), per-block partial sums (no max: |logit| tiny)
__global__ void k_logexp(const float* __restrict__ docu, const float* __restrict__ q2w,
                         const float* __restrict__ q2b, float* __restrict__ evals,
                         double* __restrict__ parts) {
    __shared__ double esh[4];
    int wvi = threadIdx.x >> 6, lane = threadIdx.x & 63;
    int v = blockIdx.x * 4 + wvi;
    if (lane == 0) esh[wvi] = 0.0;
    if (v < VOCAB) {
        const float* wr = q2w + (size_t)v * DIM;
        float4 a = *(const float4*)(wr + lane*8);
        float4 b = *(const float4*)(wr + lane*8 + 4);
        float4 da = *(const float4*)(docu + lane*8);
        float4 db = *(const float4*)(docu + lane*8 + 4);
        float p = a.x*da.x + a.y*da.y + a.z*da.z + a.w*da.w
                + b.x*db.x + b.y*db.y + b.z*db.z + b.w*db.w;
        for (int off = 32; off; off >>= 1) p += __shfl_down(p, off);
        if (lane == 0) {
            float e = expf(p + q2b[v]);
            evals[v] = e;
            esh[wvi] = (double)e;
        }
    }
    __syncthreads();
    if (threadIdx.x == 0)
        parts[blockIdx.x] = esh[0] + esh[1] + esh[2] + esh[3];
}

__global__ void k_sumred(const double* __restrict__ parts, double* __restrict__ sumv) {
    __shared__ double red[256];
    int tid = threadIdx.x;
    double s = 0.0;
    for (int i = tid; i < NPARTS; i += 256) s += parts[i];
    red[tid] = s; __syncthreads();
    for (int st = 128; st; st >>= 1) {
        if (tid < st) red[tid] += red[tid + st];
        __syncthreads();
    }
    if (tid == 0) *sumv = red[0];
}

__global__ void k_final(const float* __restrict__ evals,
                        const double* __restrict__ sumv, const unsigned* __restrict__ binc,
                        const double* __restrict__ vq_acc, const double* __restrict__ lts_acc,
                        float* __restrict__ out) {
    int v = blockIdx.x * 256 + threadIdx.x;
    if (v < VOCAB) {
        float s = (float)(*sumv);
        float p = evals[v] / s;
        out[OFF_OUT + v] = logf(p + 1e-6f) * (float)binc[v];
    }
    if (v == 0) {
        out[OFF_VQ]  = (float)(1.25 * (*vq_acc) * (1.0 / 67108864.0));
        out[OFF_LTS] = (float)((*lts_acc) * (1.0 / 262144.0));
    }
}

// ---------------------------------------------------------------------------
extern "C" void kernel_launch(void* const* d_in, const int* in_sizes, int n_in,
                              void* d_out, int out_size, void* d_ws, size_t ws_size,
                              hipStream_t stream) {
    const int*   doc = (const int*)d_in[0];
    const float* emb = (const float*)d_in[1];
    const float* cw  = (const float*)d_in[2];
    const float* q2w = (const float*)d_in[3];
    const float* q2b = (const float*)d_in[4];
    float* out = (float*)d_out;
    char* ws = (char*)d_ws;

    unsigned* counts = (unsigned*)(ws + WS_COUNTS);
    double*   vq_acc = (double*)(ws + WS_VQ);
    double*   lts_acc= (double*)(ws + WS_LTS);
    double*   sumv   = (double*)(ws + WS_SUMV);
    unsigned* nflag  = (unsigned*)(ws + WS_NFLAG);
    float*    n_arr  = (float*)(ws + WS_NARR);
    float*    s_arr  = (float*)(ws + WS_SARR);
    unsigned* binc   = (unsigned*)(ws + WS_BINC);
    float*    evals  = (float*)(ws + WS_LOGITS);
    unsigned* flags  = (unsigned*)(ws + WS_FLAGS);
    double*   parts  = (double*)(ws + WS_PART);

    short* b2;
    hipGetSymbolAddress((void**)&b2, HIP_SYMBOL(g_B2));

    hipMemsetAsync(ws, 0, 4096, stream);
    hipMemsetAsync(binc, 0, VOCAB * sizeof(unsigned), stream);

    hipLaunchKernelGGL(k_nsprep, dim3(128),  dim3(256), 0, stream, cw, n_arr, s_arr, b2);
    hipLaunchKernelGGL(k_main,   dim3(2048), dim3(256), 0, stream, doc, emb, cw, n_arr,
                       out, counts, binc, vq_acc, nflag, flags);
    hipLaunchKernelGGL(k_fixup,  dim3(256),  dim3(512), 0, stream, doc, emb, cw, n_arr,
                       nflag, flags, out, counts, vq_acc);
    hipLaunchKernelGGL(k_docu,   dim3(1),    dim3(512), 0, stream, counts, cw, out + OFF_DOCU);
    hipLaunchKernelGGL(k_lts,    dim3(128),  dim3(256), 0, stream, cw, n_arr, s_arr, lts_acc);
    hipLaunchKernelGGL(k_logexp, dim3(NPARTS), dim3(256), 0, stream,
                       out + OFF_DOCU, q2w, q2b, evals, parts);
    hipLaunchKernelGGL(k_sumred, dim3(1), dim3(256), 0, stream, parts, sumv);
    hipLaunchKernelGGL(k_final,  dim3((VOCAB + 255) / 256), dim3(256), 0, stream,
                       evals, sumv, binc, vq_acc, lts_acc, out);
}

// Round 6
// 541.709 us; speedup vs baseline: 5.4900x; 1.2179x over previous
//
#include <hip/hip_runtime.h>
#include <math.h>

#define N_TOK 131072
#define VOCAB 50257
#define DIM   512
#define K_CON 512
#define NPARTS 12565   // ceil(VOCAB/4)

// d_out layout (float32 elements)
#define OFF_ENC  ((size_t)0)
#define OFF_QW   ((size_t)67108864)
#define OFF_DOCU ((size_t)134217728)
#define OFF_OUT  ((size_t)134218240)
#define OFF_VQ   ((size_t)134268497)
#define OFF_LTS  ((size_t)134268498)

// ws layout (bytes)
#define WS_COUNTS 0        // 512 * u32
#define WS_VQ     2048     // double
#define WS_LTS    2056     // double
#define WS_SUMV   2072     // double
#define WS_NFLAG  2080     // u32
#define WS_NARR   4096     // 512 f32
#define WS_SARR   6144     // 512 f32
#define WS_BINC   8192     // VOCAB u32
#define WS_LOGITS 209920   // VOCAB f32 (holds exp(logit))
#define WS_FLAGS  411648   // FLAG_CAP u32
#define WS_PART   444416   // NPARTS double
#define FLAG_CAP  8192

typedef __attribute__((ext_vector_type(4)))  float f32x4;
typedef __attribute__((ext_vector_type(8)))  short s16x8;
typedef __attribute__((ext_vector_type(16))) float f32x16;

// Codebook in bf16 hi/lo, MFMA fragment layout:
// tile per step s (16 fp32 dims): [g 0..3][concept 0..511] x s16x8
//   g = hv for hi, 2+hv for lo ; hv selects dims s*16+hv*8..+7
// Tile stride: 16384 SHORTS = 32768 bytes.  (Round-5 bug: used 16384 BYTES.)
__device__ short g_B2[32 * 4 * 512 * 8];   // 1 MB, L2-resident

__device__ inline unsigned short f2bf(float f) {
    unsigned u = __float_as_uint(f);
    unsigned r = (u + 0x7fffu + ((u >> 16) & 1u)) >> 16;
    return (unsigned short)r;
}
__device__ inline float bf2f(unsigned short h) {
    return __uint_as_float(((unsigned)h) << 16);
}

__device__ inline void gload16(const void* g, void* l) {
    __builtin_amdgcn_global_load_lds(
        (const __attribute__((address_space(1))) unsigned int*)g,
        (__attribute__((address_space(3))) unsigned int*)l, 16, 0, 0);
}

// convert 8 fp32 (this lane's 8 dims of its token) to bf16 hi/lo fragments
__device__ __forceinline__ void conv2(const float4 a0, const float4 a1,
                                      s16x8* ah, s16x8* al) {
    float xf[8] = {a0.x,a0.y,a0.z,a0.w,a1.x,a1.y,a1.z,a1.w};
    s16x8 h, l;
    #pragma unroll
    for (int e = 0; e < 8; ++e) {
        unsigned short hb = f2bf(xf[e]);
        h[e] = (short)hb;
        l[e] = (short)f2bf(xf[e] - bf2f(hb));
    }
    *ah = h; *al = l;
}

// ---------------------------------------------------------------------------
// merged: n/s arrays + codebook bf16 hi/lo prep
__global__ void k_nsprep(const float* __restrict__ cw, float* __restrict__ n_arr,
                         float* __restrict__ s_arr, short* __restrict__ b2) {
    int w = threadIdx.x >> 6, lane = threadIdx.x & 63;
    int r = blockIdx.x * 4 + w;
    const float* row = cw + (size_t)r * DIM;
    {
        float4 a = *(const float4*)(row + lane * 8);
        float4 b = *(const float4*)(row + lane * 8 + 4);
        float v[8] = {a.x,a.y,a.z,a.w,b.x,b.y,b.z,b.w};
        double na = 0.0, sa = 0.0;
        #pragma unroll
        for (int e = 0; e < 8; ++e) { na += (double)v[e]*v[e]; sa += (double)v[e]; }
        for (int off = 32; off; off >>= 1) {
            na += __shfl_down(na, off);
            sa += __shfl_down(sa, off);
        }
        if (lane == 0) { n_arr[r] = (float)na; s_arr[r] = (float)sa; }
    }
    {
        int s = lane >> 1, hf = lane & 1;
        const float* p = row + s * 16 + hf * 8;
        float4 xa = *(const float4*)p;
        float4 xb = *(const float4*)(p + 4);
        float xf[8] = {xa.x,xa.y,xa.z,xa.w,xb.x,xb.y,xb.z,xb.w};
        s16x8 h8, l8;
        #pragma unroll
        for (int e = 0; e < 8; ++e) {
            unsigned short hb = f2bf(xf[e]);
            h8[e] = (short)hb;
            l8[e] = (short)f2bf(xf[e] - bf2f(hb));
        }
        size_t tb = (size_t)s * 16384;   // shorts
        *(s16x8*)&b2[tb + ((size_t)(hf * 512 + r)) * 8]       = h8;
        *(s16x8*)&b2[tb + ((size_t)((2 + hf) * 512 + r)) * 8] = l8;
    }
}

// ---------------------------------------------------------------------------
// Main: bf16-split MFMA distance GEMM. 512 threads = 8 waves:
//   wave wv: token group wm=wv>>2 (32 tokens), concept quarter wq=wv&3 (128).
// B in 64KB LDS double-buffer, round-3 schedule (stage next, compute, sync).
__global__ __launch_bounds__(512, 4)
void k_main(const int* __restrict__ doc, const float* __restrict__ emb,
            const float* __restrict__ cw, const float* __restrict__ n_arr,
            float* __restrict__ out, unsigned* __restrict__ counts,
            unsigned* __restrict__ binc,
            double* __restrict__ vq_acc, unsigned* __restrict__ nflag,
            unsigned* __restrict__ flag_list) {
    __shared__ s16x8 bsh[2][4 * 512];   // 64 KB double-buffered B tile
    __shared__ float nsl[512];
    __shared__ float nxs[64];
    __shared__ uint4 redv[8][64];       // 8 KB
    __shared__ int docs[64];
    __shared__ int idxs[64];
    __shared__ double dred[512];        // 4 KB

    const int tid   = threadIdx.x;
    const int n0    = blockIdx.x * 64;
    const int lane  = tid & 63;
    const int wv    = tid >> 6;
    const int wm    = wv >> 2;          // token group 0/1
    const int wq    = wv & 3;           // concept quarter
    const int hv    = lane >> 5;
    const int ln31  = lane & 31;
    const int cbase = wq * 128 + ln31;

    if (tid < 64) docs[tid] = doc[n0 + tid];
    nsl[tid] = n_arr[tid];
    __syncthreads();

#define STAGE_STEP(S, DST)                                                    \
    {                                                                         \
        const char* b2t = (const char*)g_B2 + (size_t)(S) * 32768;            \
        char* dstb = (char*)(DST);                                            \
        _Pragma("unroll")                                                     \
        for (int i = 0; i < 4; ++i)                                           \
            gload16(b2t + i * 8192 + wv * 1024 + (lane << 4),                 \
                    dstb + i * 8192 + wv * 1024);                             \
    }

    // stage step 0 into buf 0 (drained by the pre-pass barrier)
    STAGE_STEP(0, bsh[0]);

    // nx pre-pass: 8 threads per token, double partials (also warms L2)
    {
        int t = tid >> 3, q = tid & 7;
        const float* xr = emb + (size_t)docs[t] * DIM + q * 64;
        double px = 0.0;
        for (int f = 0; f < 16; ++f) {
            float4 v = *(const float4*)(xr + f * 4);
            px += (double)v.x*v.x + (double)v.y*v.y + (double)v.z*v.z + (double)v.w*v.w;
        }
        dred[tid] = px;
    }

    const float* xrow = emb + (size_t)docs[wm * 32 + ln31] * DIM;
    // prefetch A step 0 (this lane's 8 dims of its token)
    float4 a0 = *(const float4*)(xrow + hv * 8);
    float4 a1 = *(const float4*)(xrow + hv * 8 + 4);

    __syncthreads();   // drains staging 0 + A + nx loads
    if (tid < 64) {
        double s = 0.0;
        #pragma unroll
        for (int q = 0; q < 8; ++q) s += dred[tid * 8 + q];
        nxs[tid] = (float)s;
    }

    f32x16 acc[4];
    #pragma unroll
    for (int n = 0; n < 4; ++n) acc[n] = (f32x16)(0.0f);

    int cur = 0;
    for (int s = 0; s < 32; ++s) {
        // issue next-tile staging FIRST: full compute phase to complete
        if (s < 31) STAGE_STEP(s + 1, bsh[cur ^ 1]);
        // convert prefetched A
        s16x8 ah, al;
        conv2(a0, a1, &ah, &al);
        // prefetch next A
        if (s < 31) {
            const float* px = xrow + (s + 1) * 16 + hv * 8;
            a0 = *(const float4*)px;
            a1 = *(const float4*)(px + 4);
        }
        // MFMA on current buffer
        const s16x8* bb = bsh[cur];
        #pragma unroll
        for (int n = 0; n < 4; ++n) {
            s16x8 bh = bb[hv * 512 + cbase + n * 32];
            s16x8 bl = bb[(2 + hv) * 512 + cbase + n * 32];
            acc[n] = __builtin_amdgcn_mfma_f32_32x32x16_bf16(ah, bh, acc[n], 0, 0, 0);
            acc[n] = __builtin_amdgcn_mfma_f32_32x32x16_bf16(ah, bl, acc[n], 0, 0, 0);
            acc[n] = __builtin_amdgcn_mfma_f32_32x32x16_bf16(al, bh, acc[n], 0, 0, 0);
        }
        __syncthreads();   // drains staging vmcnt; buf cur reads complete
        cur ^= 1;
    }
#undef STAGE_STEP

    float nsv[4];
    #pragma unroll
    for (int n = 0; n < 4; ++n) nsv[n] = nsl[cbase + n * 32];

    // per-row argmin + second best; C/D: col=lane&31, row=(r&3)+8*(r>>2)+4*hv
    #pragma unroll
    for (int r = 0; r < 16; ++r) {
        int tt = (r & 3) + ((r >> 2) << 3) + (hv << 2);   // 0..31 within wm
        float nxr = nxs[wm * 32 + tt];
        float v1 = INFINITY, v2 = INFINITY; int j1 = 0x7fffffff;
        #pragma unroll
        for (int n = 0; n < 4; ++n) {
            float d = fmaf(-2.f, acc[n][r], nxr + nsv[n]);
            int jj = cbase + n * 32;
            if (d < v1) { v2 = v1; v1 = d; j1 = jj; }
            else if (d < v2) { v2 = d; }
        }
        #pragma unroll
        for (int off = 1; off < 32; off <<= 1) {
            float ov1 = __shfl_xor(v1, off);
            int   oj1 = __shfl_xor(j1, off);
            float ov2 = __shfl_xor(v2, off);
            v2 = fminf(fminf(v2, ov2), fmaxf(v1, ov1));
            bool take = (ov1 < v1) || (ov1 == v1 && oj1 < j1);
            if (take) { v1 = ov1; j1 = oj1; }
        }
        if (ln31 == 0)
            redv[wv][wm * 32 + tt] = make_uint4(__float_as_uint(v1), (unsigned)j1,
                                                __float_as_uint(v2), 0u);
    }
    __syncthreads();
    double myv1 = 0.0;
    if (tid < 64) {
        int g = tid >> 5;   // token group
        uint4 a = redv[g * 4][tid];
        float v1 = __uint_as_float(a.x), v2 = __uint_as_float(a.z);
        int j1 = (int)a.y;
        #pragma unroll
        for (int w = 1; w < 4; ++w) {
            uint4 b = redv[g * 4 + w][tid];
            float wv1 = __uint_as_float(b.x), wv2 = __uint_as_float(b.z);
            v2 = fminf(fminf(v2, wv2), fmaxf(v1, wv1));
            bool take = (wv1 < v1) || (wv1 == v1 && (int)b.y < j1);
            if (take) { v1 = wv1; j1 = (int)b.y; }
        }
        idxs[tid] = j1;
        atomicAdd(&counts[j1], 1u);
        atomicAdd(&binc[docs[tid]], 1u);
        myv1 = (double)v1;
        if (v2 - v1 <= 2e-7f) {
            unsigned p = atomicAdd(nflag, 1u);
            if (p < FLAG_CAP) flag_list[p] = (unsigned)(n0 + tid);
        }
    }
    dred[tid] = myv1;
    __syncthreads();

    // encodings: one-hot rows (nontemporal streaming output)
    for (int lin = tid; lin < 8192; lin += 512) {
        int t = lin >> 7, f4 = lin & 127;
        int idx = idxs[t];
        int b4 = f4 << 2;
        f32x4 v;
        v.x = (idx == b4)     ? 1.f : 0.f;
        v.y = (idx == b4 + 1) ? 1.f : 0.f;
        v.z = (idx == b4 + 2) ? 1.f : 0.f;
        v.w = (idx == b4 + 3) ? 1.f : 0.f;
        __builtin_nontemporal_store(v,
            (f32x4*)(out + OFF_ENC + ((size_t)(n0 + t) << 9) + (size_t)b4));
    }
    // quantized_words = codebook rows
    for (int lin = tid; lin < 8192; lin += 512) {
        int t = lin >> 7, f4 = lin & 127;
        f32x4 c4 = *(const f32x4*)(cw + (size_t)idxs[t] * DIM + (f4 << 2));
        __builtin_nontemporal_store(c4,
            (f32x4*)(out + OFF_QW + ((size_t)(n0 + t) << 9) + (size_t)(f4 << 2)));
    }
    // vq partial reduce
    for (int st = 256; st; st >>= 1) {
        if (tid < st) dred[tid] += dred[tid + st];
        __syncthreads();
    }
    if (tid == 0) atomicAdd(vq_acc, dred[0]);
}

// ---------------------------------------------------------------------------
// Exact fp32 recompute for flagged near-tie tokens; patches outputs in place.
__global__ __launch_bounds__(512)
void k_fixup(const int* __restrict__ doc, const float* __restrict__ emb,
             const float* __restrict__ cw, const float* __restrict__ n_arr,
             const unsigned* __restrict__ nflag, const unsigned* __restrict__ flag_list,
             float* __restrict__ out, unsigned* __restrict__ counts,
             double* __restrict__ vq_acc) {
    __shared__ float xs[512];
    __shared__ float nxsh;
    __shared__ int oldj_sh;
    __shared__ float vsh[512];
    __shared__ unsigned long long keys[512];

    const int tid = threadIdx.x;
    unsigned nf = *nflag;
    if (nf > FLAG_CAP) nf = FLAG_CAP;

    for (unsigned f = blockIdx.x; f < nf; f += gridDim.x) {
        int t = (int)flag_list[f];
        int dc = doc[t];
        if (tid < 128)
            *(float4*)&xs[tid * 4] = *(const float4*)(emb + (size_t)dc * DIM + tid * 4);
        if (tid == 0) oldj_sh = -1;
        __syncthreads();
        if (tid == 0) {
            double p[4];
            for (int q = 0; q < 4; ++q) {
                double px = 0.0;
                for (int fq = 0; fq < 32; ++fq) {
                    float4 v = *(const float4*)&xs[q * 128 + fq * 4];
                    px += (double)v.x*v.x + (double)v.y*v.y + (double)v.z*v.z + (double)v.w*v.w;
                }
                p[q] = px;
            }
            nxsh = (float)(((p[0] + p[1]) + p[2]) + p[3]);
        }
        {
            float e = out[OFF_ENC + (size_t)t * 512 + tid];
            if (e == 1.0f) oldj_sh = tid;
        }
        __syncthreads();
        {
            const float* cr = cw + (size_t)tid * DIM;
            float dot = 0.f;
            for (int d = 0; d < 512; ++d) dot = fmaf(xs[d], cr[d], dot);
            float v = fmaf(-2.f, dot, nxsh + n_arr[tid]);
            vsh[tid] = v;
            keys[tid] = (((unsigned long long)__float_as_uint(v)) << 32) | (unsigned)tid;
        }
        __syncthreads();
        for (int st = 256; st; st >>= 1) {
            if (tid < st) {
                unsigned long long o = keys[tid + st];
                if (o < keys[tid]) keys[tid] = o;
            }
            __syncthreads();
        }
        int newj = (int)(keys[0] & 0xffffffffu);
        int oldj = oldj_sh;
        if (newj != oldj) {
            if (tid == 0) {
                out[OFF_ENC + (size_t)t * 512 + oldj] = 0.0f;
                out[OFF_ENC + (size_t)t * 512 + newj] = 1.0f;
                atomicSub(&counts[oldj], 1u);
                atomicAdd(&counts[newj], 1u);
                atomicAdd(vq_acc, (double)vsh[newj] - (double)vsh[oldj]);
            }
            if (tid < 128) {
                float4 cn = *(const float4*)(cw + (size_t)newj * DIM + tid * 4);
                *(float4*)&out[OFF_QW + (size_t)t * 512 + tid * 4] = cn;
            }
        }
        __syncthreads();
    }
}

// ---------------------------------------------------------------------------
__global__ void k_docu(const unsigned* __restrict__ counts,
                       const float* __restrict__ cw, float* __restrict__ out_docu) {
    __shared__ float cnt[512];
    int tid = threadIdx.x;
    cnt[tid] = (float)counts[tid];
    __syncthreads();
    double a = 0.0;
    for (int j = 0; j < K_CON; ++j)
        a += (double)cnt[j] * (double)cw[(size_t)j * DIM + tid];
    out_docu[tid] = (float)(a * (1.0 / (double)N_TOK));
}

__global__ __launch_bounds__(256)
void k_lts(const float* __restrict__ cw, const float* __restrict__ n_arr,
           const float* __restrict__ s_arr, double* __restrict__ lts_acc) {
    __shared__ float ci[4 * 512];
    __shared__ float cjs[64 * 68];
    __shared__ double dred[256];
    const int tid = threadIdx.x;
    const int i0 = blockIdx.x * 4;
    #pragma unroll
    for (int rep = 0; rep < 2; ++rep) {
        int lin = rep * 256 + tid;
        int r = lin >> 7, fq = lin & 127;
        *(float4*)&ci[r*512 + fq*4] = *(const float4*)(cw + (size_t)(i0+r)*DIM + fq*4);
    }
    const int jj = tid & 63, ih = tid >> 6;
    const int ig = i0 + ih;
    const float ni = n_arr[ig], si = s_arr[ig];
    const float EPS = 1e-6f;
    double lsum = 0.0;
    for (int jc = 0; jc < 8; ++jc) {
        float accv = 0.f;
        for (int dc = 0; dc < 8; ++dc) {
            __syncthreads();
            #pragma unroll
            for (int rep = 0; rep < 4; ++rep) {
                int lin = rep * 256 + tid;
                int j = lin >> 4, fq = lin & 15;
                float4 v = *(const float4*)(cw + (size_t)(jc*64 + j)*DIM + dc*64 + fq*4);
                cjs[(fq*4+0)*68 + j] = v.x; cjs[(fq*4+1)*68 + j] = v.y;
                cjs[(fq*4+2)*68 + j] = v.z; cjs[(fq*4+3)*68 + j] = v.w;
            }
            __syncthreads();
            #pragma unroll 4
            for (int d = 0; d < 64; ++d)
                accv = fmaf(ci[ih*512 + dc*64 + d], cjs[d*68 + jj], accv);
        }
        int jg = jc*64 + jj;
        float ddv = ni + n_arr[jg] - 2.f*accv + 2.f*EPS*(si - s_arr[jg]) + 512.f*EPS*EPS;
        float dist = sqrtf(fmaxf(ddv, 0.f));
        lsum += (double)((ig == jg) ? dist : fmaxf(0.f, 1.f - dist));
    }
    dred[tid] = lsum;
    __syncthreads();
    for (int s = 128; s; s >>= 1) {
        if (tid < s) dred[tid] += dred[tid + s];
        __syncthreads();
    }
    if (tid == 0) atomicAdd(lts_acc, dred[0]);
}

// logits -> e = exp(logit + bias), per-block partial sums (no max: |logit| tiny)
__global__ void k_logexp(const float* __restrict__ docu, const float* __restrict__ q2w,
                         const float* __restrict__ q2b, float* __restrict__ evals,
                         double* __restrict__ parts) {
    __shared__ double esh[4];
    int wvi = threadIdx.x >> 6, lane = threadIdx.x & 63;
    int v = blockIdx.x * 4 + wvi;
    if (lane == 0) esh[wvi] = 0.0;
    if (v < VOCAB) {
        const float* wr = q2w + (size_t)v * DIM;
        float4 a = *(const float4*)(wr + lane*8);
        float4 b = *(const float4*)(wr + lane*8 + 4);
        float4 da = *(const float4*)(docu + lane*8);
        float4 db = *(const float4*)(docu + lane*8 + 4);
        float p = a.x*da.x + a.y*da.y + a.z*da.z + a.w*da.w
                + b.x*db.x + b.y*db.y + b.z*db.z + b.w*db.w;
        for (int off = 32; off; off >>= 1) p += __shfl_down(p, off);
        if (lane == 0) {
            float e = expf(p + q2b[v]);
            evals[v] = e;
            esh[wvi] = (double)e;
        }
    }
    __syncthreads();
    if (threadIdx.x == 0)
        parts[blockIdx.x] = esh[0] + esh[1] + esh[2] + esh[3];
}

__global__ void k_sumred(const double* __restrict__ parts, double* __restrict__ sumv) {
    __shared__ double red[256];
    int tid = threadIdx.x;
    double s = 0.0;
    for (int i = tid; i < NPARTS; i += 256) s += parts[i];
    red[tid] = s; __syncthreads();
    for (int st = 128; st; st >>= 1) {
        if (tid < st) red[tid] += red[tid + st];
        __syncthreads();
    }
    if (tid == 0) *sumv = red[0];
}

__global__ void k_final(const float* __restrict__ evals,
                        const double* __restrict__ sumv, const unsigned* __restrict__ binc,
                        const double* __restrict__ vq_acc, const double* __restrict__ lts_acc,
                        float* __restrict__ out) {
    int v = blockIdx.x * 256 + threadIdx.x;
    if (v < VOCAB) {
        float s = (float)(*sumv);
        float p = evals[v] / s;
        out[OFF_OUT + v] = logf(p + 1e-6f) * (float)binc[v];
    }
    if (v == 0) {
        out[OFF_VQ]  = (float)(1.25 * (*vq_acc) * (1.0 / 67108864.0));
        out[OFF_LTS] = (float)((*lts_acc) * (1.0 / 262144.0));
    }
}

// ---------------------------------------------------------------------------
extern "C" void kernel_launch(void* const* d_in, const int* in_sizes, int n_in,
                              void* d_out, int out_size, void* d_ws, size_t ws_size,
                              hipStream_t stream) {
    const int*   doc = (const int*)d_in[0];
    const float* emb = (const float*)d_in[1];
    const float* cw  = (const float*)d_in[2];
    const float* q2w = (const float*)d_in[3];
    const float* q2b = (const float*)d_in[4];
    float* out = (float*)d_out;
    char* ws = (char*)d_ws;

    unsigned* counts = (unsigned*)(ws + WS_COUNTS);
    double*   vq_acc = (double*)(ws + WS_VQ);
    double*   lts_acc= (double*)(ws + WS_LTS);
    double*   sumv   = (double*)(ws + WS_SUMV);
    unsigned* nflag  = (unsigned*)(ws + WS_NFLAG);
    float*    n_arr  = (float*)(ws + WS_NARR);
    float*    s_arr  = (float*)(ws + WS_SARR);
    unsigned* binc   = (unsigned*)(ws + WS_BINC);
    float*    evals  = (float*)(ws + WS_LOGITS);
    unsigned* flags  = (unsigned*)(ws + WS_FLAGS);
    double*   parts  = (double*)(ws + WS_PART);

    short* b2;
    hipGetSymbolAddress((void**)&b2, HIP_SYMBOL(g_B2));

    hipMemsetAsync(ws, 0, 4096, stream);
    hipMemsetAsync(binc, 0, VOCAB * sizeof(unsigned), stream);

    hipLaunchKernelGGL(k_nsprep, dim3(128),  dim3(256), 0, stream, cw, n_arr, s_arr, b2);
    hipLaunchKernelGGL(k_main,   dim3(2048), dim3(512), 0, stream, doc, emb, cw, n_arr,
                       out, counts, binc, vq_acc, nflag, flags);
    hipLaunchKernelGGL(k_fixup,  dim3(256),  dim3(512), 0, stream, doc, emb, cw, n_arr,
                       nflag, flags, out, counts, vq_acc);
    hipLaunchKernelGGL(k_docu,   dim3(1),    dim3(512), 0, stream, counts, cw, out + OFF_DOCU);
    hipLaunchKernelGGL(k_lts,    dim3(128),  dim3(256), 0, stream, cw, n_arr, s_arr, lts_acc);
    hipLaunchKernelGGL(k_logexp, dim3(NPARTS), dim3(256), 0, stream,
                       out + OFF_DOCU, q2w, q2b, evals, parts);
    hipLaunchKernelGGL(k_sumred, dim3(1), dim3(256), 0, stream, parts, sumv);
    hipLaunchKernelGGL(k_final,  dim3((VOCAB + 255) / 256), dim3(256), 0, stream,
                       evals, sumv, binc, vq_acc, lts_acc, out);
}